// Round 14
// baseline (2004.064 us; speedup 1.0000x reference)
//
#include <hip/hip_runtime.h>

// Problem constants (fixed by the reference).
#define TSTEPS 256
#define NNODE  100000
#define NEDGE  8192

constexpr float MU_P  = 0.1f;
constexpr float MU_M  = 0.05f;
constexpr float RHO_  = 16.0f;
constexpr float CLO   = 1e-5f;
constexpr float CHI   = 1.0f - 1e-5f;
constexpr float SCALE = 1048576.0f;          // 2^20 fixed-point for delta
constexpr float INVSC = 1.0f / 1048576.0f;

// f32 sentinel: real X values are positive finite, 0xFFFFFFFF impossible.
#define SENT32 0xFFFFFFFFu

typedef unsigned long long u64;

__device__ __forceinline__ float sigm(float x) {
  return 1.0f / (1.0f + __expf(-x));
}
__device__ __forceinline__ float x0_of(const float* logit, int n) {
  return fminf(fmaxf(sigm(logit[n]), CLO), CHI);
}
__device__ __forceinline__ int edge_at(const int* __restrict__ arr, int idx,
                                       int is64) {
  if (is64) return (int)((const long long*)arr)[idx];
  return arr[idx];
}

// 8-byte atomic pair ops (no tearing); workgroup scope -> plain cached
// dwordx2 (R11 proved agent-scope loads bypass caches at ~1.4 GB HBM cost).
// Stale pairs are CORRECT here: old tag -> combine path reproduces the value.
__device__ __forceinline__ u64 pload(const u64* p) {
  return __hip_atomic_load(p, __ATOMIC_RELAXED, __HIP_MEMORY_SCOPE_WORKGROUP);
}
__device__ __forceinline__ void pstore(u64* p, u64 v) {
  __hip_atomic_store(p, v, __ATOMIC_RELAXED, __HIP_MEMORY_SCOPE_WORKGROUP);
}

// ---------------------------------------------------------------------------
// k_init: state + deltas + output X row0/sentinel init; thread 0 runs the
// int32/int64 edge-width probe. Re-runs every call -> deterministic replays.
// ---------------------------------------------------------------------------
__global__ void k_init(const float* __restrict__ logit,
                       const int* __restrict__ u, const int* __restrict__ v,
                       u64* __restrict__ xs64,
                       unsigned* __restrict__ d0, unsigned* __restrict__ d1,
                       unsigned* __restrict__ d2,
                       unsigned* __restrict__ dflags,
                       float* __restrict__ outX) {
  const int i = blockIdx.x * blockDim.x + threadIdx.x;
  const int stride = gridDim.x * blockDim.x;

  if (i == 0) {   // folded detect probe
    const unsigned* a = (const unsigned*)u;
    const unsigned* b = (const unsigned*)v;
    bool i64 = true;
    for (int k = 1; k < 128; k += 2) i64 = i64 && (a[k] == 0u) && (b[k] == 0u);
    dflags[0] = i64 ? 1u : 0u;
  }

  for (int n = i; n < NNODE; n += stride) {
    xs64[n] = (u64)__float_as_uint(x0_of(logit, n));   // tag 0 in high word
    d0[n] = 0u;
    d1[n] = 0u;
    d2[n] = 0u;
    outX[n] = sigm(logit[n]);            // row 0, unclipped, f32
  }
  unsigned* outX32 = (unsigned*)outX;
  const int total = TSTEPS * NNODE;
  for (int w = NNODE + i; w < total; w += stride) outX32[w] = SENT32;
}

// ---------------------------------------------------------------------------
// k_step (ONE dispatch per timestep t; cross-step visibility = the proven
// dispatch boundary). 2E threads, three slim jobs:
//  A (s<E, t<T-1): gather edge (t,s) via lazy x_t; accumulate dcur.
//  B (t>=1): apply endpoint s of row t-1: val=lazy(node); xs64[node]={t,val};
//            cvals[(t-1)*2E+s]=val  (COALESCED -- random outX scatter moved
//            to the k_scatter post-pass, off the serial chain).
//  C (t>=2): zero dzero at endpoint s of row t-2 (that buffer's dirty set).
// lazy(n): {tag,val}=xs64[n]; tag==t ? val : clip(val + dprev[n]*2^-20).
// ---------------------------------------------------------------------------
__global__ void k_step(const int* __restrict__ u, const int* __restrict__ v,
                       const float* __restrict__ sp, const float* __restrict__ sm,
                       u64* __restrict__ xs64,
                       unsigned* __restrict__ d0, unsigned* __restrict__ d1,
                       unsigned* __restrict__ d2,
                       float* __restrict__ cvals,
                       const unsigned* __restrict__ dflags, int t) {
  const int s = blockIdx.x * blockDim.x + threadIdx.x;   // 0..2*NEDGE-1
  const int is64 = (int)dflags[0];

  unsigned* dbuf[3] = {d0, d1, d2};
  unsigned* dcur  = dbuf[t % 3];
  unsigned* dprev = dbuf[(t + 2) % 3];
  unsigned* dzero = dbuf[(t + 1) % 3];

  const unsigned ttag = (unsigned)t;

  auto lazy = [&](int n) -> float {
    const u64 a = pload(&xs64[n]);
    const unsigned tag = (unsigned)(a >> 32);
    float val = __uint_as_float((unsigned)a);
    if (tag != ttag) {
      const int acc = (int)dprev[n];
      val = fminf(fmaxf(val + (float)acc * INVSC, CLO), CHI);
    }
    return val;
  };

  // ---- Job A: gather + accumulate (edges of row t) ----
  if (s < NEDGE && t < TSTEPS - 1) {
    const int e  = t * NEDGE + s;
    const int un = edge_at(u, e, is64);
    const int vn = edge_at(v, e, is64);
    const float xu = lazy(un);
    const float xv = lazy(vn);
    const float w  = MU_P * sp[e] - MU_M * sm[e];
    const int   iv = __float2int_rn(w * (xv - xu) * SCALE);
    atomicAdd(&dcur[un], (unsigned)iv);      // HW-coherent RMW (proven)
    atomicAdd(&dcur[vn], (unsigned)(-iv));
  }

  // ---- Job B: apply endpoints of row t-1; persist pair + compact write ----
  if (t >= 1) {
    const int e2 = (t - 1) * NEDGE + (s < NEDGE ? s : s - NEDGE);
    const int node = (s < NEDGE) ? edge_at(u, e2, is64) : edge_at(v, e2, is64);
    const float val = lazy(node);
    pstore(&xs64[node], ((u64)ttag << 32) | (u64)__float_as_uint(val));
    cvals[(size_t)(t - 1) * (2 * NEDGE) + s] = val;   // coalesced
  }

  // ---- Job C: zero dzero at endpoints of row t-2 (ready for step t+1) ----
  if (t >= 2) {
    const int e3 = (t - 2) * NEDGE + (s < NEDGE ? s : s - NEDGE);
    const int node = (s < NEDGE) ? edge_at(u, e3, is64) : edge_at(v, e3, is64);
    dzero[node] = 0u;
  }
}

// ---------------------------------------------------------------------------
// k_scatter: compact -> dense, fully parallel (255 rows x 2E slots at full
// occupancy, OFF the serial chain). Duplicates write identical bits (benign).
// Slot s of row r holds x_{r+1}(node) -> outX row r+1.
// ---------------------------------------------------------------------------
__global__ void k_scatter(const int* __restrict__ u, const int* __restrict__ v,
                          const float* __restrict__ cvals,
                          float* __restrict__ outX,
                          const unsigned* __restrict__ dflags) {
  const int g = blockIdx.x * blockDim.x + threadIdx.x;   // 0..255*2E-1
  if (g >= (TSTEPS - 1) * 2 * NEDGE) return;
  const int is64 = (int)dflags[0];
  const int r = g / (2 * NEDGE);                         // row 0..254
  const int s = g - r * (2 * NEDGE);
  const int e = r * NEDGE + (s < NEDGE ? s : s - NEDGE);
  const int node = (s < NEDGE) ? edge_at(u, e, is64) : edge_at(v, e, is64);
  outX[(size_t)(r + 1) * NNODE + node] = cvals[g];
}

// ---------------------------------------------------------------------------
// k_fill: resolve sentinels by fill-forward; coalesced per-node columns.
// ---------------------------------------------------------------------------
__global__ void k_fill(const float* __restrict__ logit,
                       unsigned* __restrict__ outX32) {
  const int n = blockIdx.x * blockDim.x + threadIdx.x;
  if (n >= NNODE) return;
  unsigned carry = __float_as_uint(x0_of(logit, n));   // untouched = clip(X0)
  for (int t = 1; t < TSTEPS; ++t) {
    const size_t idx = (size_t)t * NNODE + n;
    const unsigned w = outX32[idx];
    if (w == SENT32) outX32[idx] = carry;
    else             carry = w;
  }
}

// ---------------------------------------------------------------------------
// k_kappa: massively-parallel kappa over ALL T*E edges from the filled dense
// X. Runs LAST: it overwrites the kappa region that temporarily held cvals.
// ---------------------------------------------------------------------------
__global__ void k_kappa(const int* __restrict__ u, const int* __restrict__ v,
                        const float* __restrict__ theta,
                        const float* __restrict__ X,
                        float* __restrict__ outKp, float* __restrict__ outKm,
                        const unsigned* __restrict__ dflags) {
  const int g = blockIdx.x * blockDim.x + threadIdx.x;   // 0..T*E-1
  const int is64 = (int)dflags[0];
  const int t  = g >> 13;                                // / NEDGE (2^13)
  const int un = edge_at(u, g, is64);
  const int vn = edge_at(v, g, is64);
  const float Xu = X[(size_t)t * NNODE + un];
  const float Xv = X[(size_t)t * NNODE + vn];
  const float ad = fabsf(Xu - Xv);
  const float epsp = sigm(theta[0]) * 0.5f;
  const float epsm = 0.5f + sigm(theta[1]) * 0.5f;
  outKp[g] = sigm(RHO_ * (epsp - ad));
  outKm[g] = sigm(RHO_ * (ad - epsm));
}

// ---------------------------------------------------------------------------
// kDiag: forced host-probe failure encoding only (layout/ws sanity).
// ---------------------------------------------------------------------------
__global__ void kDiag(float* __restrict__ outX, int b0, int b1) {
  if (threadIdx.x != 0 || blockIdx.x != 0) return;
  outX[0] = (float)(2048 + 1024 * b0 + 512 * b1);
}

// ---------------------------------------------------------------------------
extern "C" void kernel_launch(void* const* d_in, const int* in_sizes, int n_in,
                              void* d_out, int out_size, void* d_ws, size_t ws_size,
                              hipStream_t stream) {
  const float* logit = (const float*)d_in[0];
  const float* theta = (const float*)d_in[1];
  const int*   u     = (const int*)d_in[2];
  const int*   v     = (const int*)d_in[3];
  const float* sp    = (const float*)d_in[4];
  const float* sm    = (const float*)d_in[5];

  float* outX  = (float*)d_out;                         // [T, N] f32
  float* outKp = outX + (size_t)TSTEPS * NNODE;         // [T, E] f32
  float* outKm = outKp + (size_t)TSTEPS * NEDGE;        // [T, E] f32

  // cvals scratch lives in the kappa output region: 255*2E f32 = 16.71 MB
  // <= outKp+outKm = 16.78 MB. k_kappa runs last and overwrites it.
  float* cvals = outKp;

  const int b0 = (n_in == 6 &&
                  in_sizes[0] == NNODE && in_sizes[1] == 2 &&
                  in_sizes[2] == TSTEPS * NEDGE && in_sizes[3] == TSTEPS * NEDGE &&
                  in_sizes[4] == TSTEPS * NEDGE && in_sizes[5] == TSTEPS * NEDGE) ? 1 : 0;
  const size_t WS_NEED = (size_t)NNODE * 8 + (size_t)3 * NNODE * 4 + 64;
  const int b1 = (ws_size >= WS_NEED) ? 1 : 0;
  if (!b0 || !b1) {
    kDiag<<<1, 64, 0, stream>>>(outX, b0, b1);
    return;
  }

  // workspace: xs64 (N u64) | d0 | d1 | d2 (N u32 each) | dflags (8 u32)
  char* ws = (char*)d_ws;
  u64*      xs64   = (u64*)ws;
  unsigned* d0     = (unsigned*)(ws + (size_t)NNODE * 8);
  unsigned* d1     = (unsigned*)(ws + (size_t)NNODE * 8 + (size_t)NNODE * 4);
  unsigned* d2     = (unsigned*)(ws + (size_t)NNODE * 8 + (size_t)2 * NNODE * 4);
  unsigned* dflags = (unsigned*)(ws + (size_t)NNODE * 8 + (size_t)3 * NNODE * 4);

  k_init<<<2048, 256, 0, stream>>>(logit, u, v, xs64, d0, d1, d2, dflags, outX);

  for (int t = 0; t < TSTEPS; ++t) {
    k_step<<<(2 * NEDGE) / 256, 256, 0, stream>>>(u, v, sp, sm, xs64,
                                                  d0, d1, d2, cvals,
                                                  dflags, t);
  }

  k_scatter<<<((TSTEPS - 1) * 2 * NEDGE + 255) / 256, 256, 0, stream>>>(
      u, v, cvals, outX, dflags);
  k_fill<<<(NNODE + 255) / 256, 256, 0, stream>>>(logit, (unsigned*)d_out);
  k_kappa<<<(TSTEPS * NEDGE) / 256, 256, 0, stream>>>(u, v, theta, outX,
                                                      outKp, outKm, dflags);
}

// Round 15
// 1526.254 us; speedup vs baseline: 1.3131x; 1.3131x over previous
//
#include <hip/hip_runtime.h>

// Problem constants (fixed by the reference).
#define TSTEPS 256
#define NNODE  100000
#define NEDGE  8192

constexpr float MU_P  = 0.1f;
constexpr float MU_M  = 0.05f;
constexpr float RHO_  = 16.0f;
constexpr float CLO   = 1e-5f;
constexpr float CHI   = 1.0f - 1e-5f;
constexpr float SCALE = 1048576.0f;          // 2^20 fixed-point for delta
constexpr float INVSC = 1.0f / 1048576.0f;

// f32 sentinel: real X values are positive finite, 0xFFFFFFFF impossible.
#define SENT32 0xFFFFFFFFu

typedef unsigned long long u64;

__device__ __forceinline__ float sigm(float x) {
  return 1.0f / (1.0f + __expf(-x));
}
__device__ __forceinline__ float x0_of(const float* logit, int n) {
  return fminf(fmaxf(sigm(logit[n]), CLO), CHI);
}
__device__ __forceinline__ int edge_at(const int* __restrict__ arr, int idx,
                                       int is64) {
  if (is64) return (int)((const long long*)arr)[idx];
  return arr[idx];
}

// 8-byte atomic pair ops (no tearing); workgroup scope -> plain cached
// dwordx2. Stale pairs are CORRECT: old tag -> catch-up path (R12-proven).
__device__ __forceinline__ u64 pload(const u64* p) {
  return __hip_atomic_load(p, __ATOMIC_RELAXED, __HIP_MEMORY_SCOPE_WORKGROUP);
}
__device__ __forceinline__ void pstore(u64* p, u64 v) {
  __hip_atomic_store(p, v, __ATOMIC_RELAXED, __HIP_MEMORY_SCOPE_WORKGROUP);
}

// parallel-load lazy: both loads issued before the tag select.
__device__ __forceinline__ float lazy2(const u64* xs64,
                                       const unsigned* __restrict__ dprev,
                                       int n, unsigned ttag) {
  const u64 a = pload(&xs64[n]);          // independent loads: the compiler
  const int acc = (int)dprev[n];          // can issue both before waiting
  const unsigned tag = (unsigned)(a >> 32);
  const float pv = __uint_as_float((unsigned)a);
  const float cu = fminf(fmaxf(pv + (float)acc * INVSC, CLO), CHI);
  return (tag == ttag) ? pv : cu;
}

// ---------------------------------------------------------------------------
// k_init: pairs {tag0, clip(sigmoid)}; d0/d1/d2 zero; flags probe; outX row 0
// + sentinel rows 1..T-1. Re-runs every call -> deterministic replays.
// ---------------------------------------------------------------------------
__global__ void k_init(const float* __restrict__ logit,
                       const int* __restrict__ u, const int* __restrict__ v,
                       u64* __restrict__ xs64,
                       unsigned* __restrict__ d0, unsigned* __restrict__ d1,
                       unsigned* __restrict__ d2,
                       unsigned* __restrict__ dflags,
                       float* __restrict__ outX) {
  const int i = blockIdx.x * blockDim.x + threadIdx.x;
  const int stride = gridDim.x * blockDim.x;

  if (i == 0) {   // int width probe
    const unsigned* a = (const unsigned*)u;
    const unsigned* b = (const unsigned*)v;
    bool i64 = true;
    for (int k = 1; k < 128; k += 2) i64 = i64 && (a[k] == 0u) && (b[k] == 0u);
    dflags[0] = i64 ? 1u : 0u;
  }

  for (int n = i; n < NNODE; n += stride) {
    xs64[n] = (u64)__float_as_uint(x0_of(logit, n));   // tag 0
    d0[n] = 0u;
    d1[n] = 0u;
    d2[n] = 0u;
    outX[n] = sigm(logit[n]);            // row 0, unclipped, f32
  }
  unsigned* outX32 = (unsigned*)outX;
  const int total = TSTEPS * NNODE;
  for (int w = NNODE + i; w < total; w += stride) outX32[w] = SENT32;
}

// ---------------------------------------------------------------------------
// k_prep: materialize int32 edge ids + premultiplied weights into the outX
// tail scratch (rows 1..63 of outX are sentinel garbage until post-passes;
// k_resent restores them). Removes is64 branch + sp/sm loads + w arithmetic
// from the 256 serial dispatches.
// ---------------------------------------------------------------------------
__global__ void k_prep(const int* __restrict__ u, const int* __restrict__ v,
                       const float* __restrict__ sp, const float* __restrict__ sm,
                       int* __restrict__ uv32u, int* __restrict__ uv32v,
                       float* __restrict__ wsc,
                       const unsigned* __restrict__ dflags) {
  const int g = blockIdx.x * blockDim.x + threadIdx.x;   // 0..T*E-1
  if (g >= TSTEPS * NEDGE) return;
  const int is64 = (int)dflags[0];
  uv32u[g] = edge_at(u, g, is64);
  uv32v[g] = edge_at(v, g, is64);
  wsc[g] = (MU_P * sp[g] - MU_M * sm[g]) * SCALE;
}

// ---------------------------------------------------------------------------
// k_step (ONE dispatch per timestep t; cross-step visibility = the proven
// dispatch boundary). Role-partitioned blocks of 256 threads:
//   blocks [0,32):  A — edge e=(t,i): iv = rn(wsc*(xv-xu)); atomicAdd dcur.
//   blocks [32,96): B — apply endpoint slot j of row t-1: val = lazy;
//                   pstore {t,val}; cvals[(t-1)*2E+j] = val (coalesced).
//   blocks [96,160):C — dense-zero dzero (row t+1's buffer, idle this step).
// Buffer rotation is done on the HOST (no runtime-indexed pointer array ->
// no scratch spill, rule #20).
// ---------------------------------------------------------------------------
__global__ __launch_bounds__(256) void k_step(
    const int* __restrict__ uv32u, const int* __restrict__ uv32v,
    const float* __restrict__ wsc,
    u64* __restrict__ xs64,
    unsigned* __restrict__ dcur, const unsigned* __restrict__ dprev,
    unsigned* __restrict__ dzero,
    float* __restrict__ cvals, int t) {
  const int bid = blockIdx.x;
  const int tid = threadIdx.x;
  const unsigned ttag = (unsigned)t;

  if (bid < 32) {
    // ---- A: gather + accumulate (edges of row t) ----
    if (t < TSTEPS - 1) {
      const int i = bid * 256 + tid;            // 0..8191
      const int e = t * NEDGE + i;
      const int un = uv32u[e];
      const int vn = uv32v[e];
      const float w = wsc[e];
      const float xu = lazy2(xs64, dprev, un, ttag);
      const float xv = lazy2(xs64, dprev, vn, ttag);
      const int iv = __float2int_rn(w * (xv - xu));
      atomicAdd(&dcur[un], (unsigned)iv);
      atomicAdd(&dcur[vn], (unsigned)(-iv));
    }
  } else if (bid < 96) {
    // ---- B: apply endpoints of row t-1; persist pair + compact write ----
    if (t >= 1) {
      const int j = (bid - 32) * 256 + tid;     // 0..16383
      const int e2 = (t - 1) * NEDGE + (j < NEDGE ? j : j - NEDGE);
      const int node = (j < NEDGE) ? uv32u[e2] : uv32v[e2];
      const float val = lazy2(xs64, dprev, node, ttag);
      pstore(&xs64[node], ((u64)ttag << 32) | (u64)__float_as_uint(val));
      cvals[(size_t)(t - 1) * (2 * NEDGE) + j] = val;   // coalesced
    }
  } else {
    // ---- C: dense-zero the idle buffer (used next step as dcur) ----
    const int base = (bid - 96) * 256 + tid;    // 0..16383
    for (int n = base; n < NNODE; n += 64 * 256) dzero[n] = 0u;
  }
}

// ---------------------------------------------------------------------------
// k_resent: restore sentinel over the outX-tail scratch region (uv32/wsc),
// BEFORE k_scatter writes real values into those rows.
// ---------------------------------------------------------------------------
__global__ void k_resent(unsigned* __restrict__ outX32) {
  const int g = blockIdx.x * blockDim.x + threadIdx.x;
  const int total = 3 * TSTEPS * NEDGE;          // 3 scratch arrays of T*E
  for (int w = g; w < total; w += gridDim.x * blockDim.x) {
    outX32[NNODE + w] = SENT32;
  }
}

// ---------------------------------------------------------------------------
// k_scatter: compact -> dense, fully parallel. Reads ORIGINAL u/v (scratch
// may be mid-overwrite by our own dense writes). Duplicates identical-bits.
// ---------------------------------------------------------------------------
__global__ void k_scatter(const int* __restrict__ u, const int* __restrict__ v,
                          const float* __restrict__ cvals,
                          float* __restrict__ outX,
                          const unsigned* __restrict__ dflags) {
  const int g = blockIdx.x * blockDim.x + threadIdx.x;   // 0..255*2E-1
  if (g >= (TSTEPS - 1) * 2 * NEDGE) return;
  const int is64 = (int)dflags[0];
  const int r = g / (2 * NEDGE);                         // row 0..254
  const int s = g - r * (2 * NEDGE);
  const int e = r * NEDGE + (s < NEDGE ? s : s - NEDGE);
  const int node = (s < NEDGE) ? edge_at(u, e, is64) : edge_at(v, e, is64);
  outX[(size_t)(r + 1) * NNODE + node] = cvals[g];
}

// ---------------------------------------------------------------------------
// k_fill: resolve sentinels by fill-forward; coalesced per-node columns.
// ---------------------------------------------------------------------------
__global__ void k_fill(const float* __restrict__ logit,
                       unsigned* __restrict__ outX32) {
  const int n = blockIdx.x * blockDim.x + threadIdx.x;
  if (n >= NNODE) return;
  unsigned carry = __float_as_uint(x0_of(logit, n));   // untouched = clip(X0)
  for (int t = 1; t < TSTEPS; ++t) {
    const size_t idx = (size_t)t * NNODE + n;
    const unsigned w = outX32[idx];
    if (w == SENT32) outX32[idx] = carry;
    else             carry = w;
  }
}

// ---------------------------------------------------------------------------
// k_kappa: massively-parallel kappa from the filled dense X. Runs LAST; it
// overwrites the kappa region that temporarily held cvals.
// ---------------------------------------------------------------------------
__global__ void k_kappa(const int* __restrict__ u, const int* __restrict__ v,
                        const float* __restrict__ theta,
                        const float* __restrict__ X,
                        float* __restrict__ outKp, float* __restrict__ outKm,
                        const unsigned* __restrict__ dflags) {
  const int g = blockIdx.x * blockDim.x + threadIdx.x;   // 0..T*E-1
  const int is64 = (int)dflags[0];
  const int t  = g >> 13;                                // / NEDGE
  const int un = edge_at(u, g, is64);
  const int vn = edge_at(v, g, is64);
  const float Xu = X[(size_t)t * NNODE + un];
  const float Xv = X[(size_t)t * NNODE + vn];
  const float ad = fabsf(Xu - Xv);
  const float epsp = sigm(theta[0]) * 0.5f;
  const float epsm = 0.5f + sigm(theta[1]) * 0.5f;
  outKp[g] = sigm(RHO_ * (epsp - ad));
  outKm[g] = sigm(RHO_ * (ad - epsm));
}

// ---------------------------------------------------------------------------
// kDiag: forced host-probe failure encoding only (layout/ws sanity).
// ---------------------------------------------------------------------------
__global__ void kDiag(float* __restrict__ outX, int b0, int b1) {
  if (threadIdx.x != 0 || blockIdx.x != 0) return;
  outX[0] = (float)(2048 + 1024 * b0 + 512 * b1);
}

// ---------------------------------------------------------------------------
extern "C" void kernel_launch(void* const* d_in, const int* in_sizes, int n_in,
                              void* d_out, int out_size, void* d_ws, size_t ws_size,
                              hipStream_t stream) {
  const float* logit = (const float*)d_in[0];
  const float* theta = (const float*)d_in[1];
  const int*   u     = (const int*)d_in[2];
  const int*   v     = (const int*)d_in[3];
  const float* sp    = (const float*)d_in[4];
  const float* sm    = (const float*)d_in[5];

  float* outX  = (float*)d_out;                         // [T, N] f32
  float* outKp = outX + (size_t)TSTEPS * NNODE;         // [T, E] f32
  float* outKm = outKp + (size_t)TSTEPS * NEDGE;        // [T, E] f32

  // cvals scratch: kappa region (16.71 <= 16.78 MB; k_kappa overwrites last).
  float* cvals = outKp;

  // outX-tail scratch (rows 1..63 area, re-sentineled by k_resent):
  int*   uv32u = (int*)(outX + NNODE);
  int*   uv32v = uv32u + (size_t)TSTEPS * NEDGE;
  float* wsc   = (float*)(uv32v + (size_t)TSTEPS * NEDGE);

  const int b0 = (n_in == 6 &&
                  in_sizes[0] == NNODE && in_sizes[1] == 2 &&
                  in_sizes[2] == TSTEPS * NEDGE && in_sizes[3] == TSTEPS * NEDGE &&
                  in_sizes[4] == TSTEPS * NEDGE && in_sizes[5] == TSTEPS * NEDGE) ? 1 : 0;
  const size_t WS_NEED = (size_t)NNODE * 8 + (size_t)3 * NNODE * 4 + 64;
  const int b1 = (ws_size >= WS_NEED) ? 1 : 0;
  if (!b0 || !b1) {
    kDiag<<<1, 64, 0, stream>>>(outX, b0, b1);
    return;
  }

  // workspace: xs64 (N u64) | d0 | d1 | d2 (N u32 each) | dflags (8 u32)
  char* ws = (char*)d_ws;
  u64*      xs64   = (u64*)ws;
  unsigned* d0     = (unsigned*)(ws + (size_t)NNODE * 8);
  unsigned* d1     = (unsigned*)(ws + (size_t)NNODE * 8 + (size_t)NNODE * 4);
  unsigned* d2     = (unsigned*)(ws + (size_t)NNODE * 8 + (size_t)2 * NNODE * 4);
  unsigned* dflags = (unsigned*)(ws + (size_t)NNODE * 8 + (size_t)3 * NNODE * 4);
  unsigned* dbuf[3] = {d0, d1, d2};

  k_init<<<2048, 256, 0, stream>>>(logit, u, v, xs64, d0, d1, d2, dflags, outX);
  k_prep<<<(TSTEPS * NEDGE + 255) / 256, 256, 0, stream>>>(u, v, sp, sm,
                                                           uv32u, uv32v, wsc,
                                                           dflags);

  for (int t = 0; t < TSTEPS; ++t) {
    // host-side rotation: no runtime-indexed pointer arrays in the kernel
    unsigned* dcur  = dbuf[t % 3];
    unsigned* dprev = dbuf[(t + 2) % 3];
    unsigned* dzero = dbuf[(t + 1) % 3];
    k_step<<<160, 256, 0, stream>>>(uv32u, uv32v, wsc, xs64,
                                    dcur, dprev, dzero, cvals, t);
  }

  k_resent<<<4096, 256, 0, stream>>>((unsigned*)d_out);
  k_scatter<<<((TSTEPS - 1) * 2 * NEDGE + 255) / 256, 256, 0, stream>>>(
      u, v, cvals, outX, dflags);
  k_fill<<<(NNODE + 255) / 256, 256, 0, stream>>>(logit, (unsigned*)d_out);
  k_kappa<<<(TSTEPS * NEDGE) / 256, 256, 0, stream>>>(u, v, theta, outX,
                                                      outKp, outKm, dflags);
}